// Round 5
// baseline (1132.665 us; speedup 1.0000x reference)
//
#include <hip/hip_runtime.h>

typedef unsigned short ushort_t;
typedef __attribute__((ext_vector_type(8))) short short8;
typedef __attribute__((ext_vector_type(4))) float f32x4;

#define DEV __device__ __forceinline__

DEV unsigned short f2bf(float f) {
  unsigned int u = __float_as_uint(f);
  u += 0x7FFFu + ((u >> 16) & 1u);           // round-to-nearest-even
  return (unsigned short)(u >> 16);
}
DEV float bf2f(unsigned short h) { return __uint_as_float(((unsigned int)h) << 16); }

DEV void gload_lds16(const void* g, void* l) {
  __builtin_amdgcn_global_load_lds((const __attribute__((address_space(1))) void*)g,
                                   (__attribute__((address_space(3))) void*)l, 16, 0, 0);
}

// ---------------------------------------------------------------- converts
__global__ void cvt_x_k(const float4* __restrict__ in, ushort4* __restrict__ out) {
  const int i = blockIdx.x * 256 + threadIdx.x;
  float4 f = in[i];
  out[i] = make_ushort4(f2bf(f.x), f2bf(f.y), f2bf(f.z), f2bf(f.w));
}

// in [R][Cn] f32 -> out [Cn][R] bf16   (tiled transpose)
__global__ __launch_bounds__(256)
void transp_k(const float* __restrict__ in, ushort_t* __restrict__ out, int R, int Cn) {
  __shared__ float tile[32][33];
  const int ctiles = Cn >> 5;
  const int bx = blockIdx.x % ctiles;
  const int by = blockIdx.x / ctiles;
  const int tx = threadIdx.x & 31, ty = threadIdx.x >> 5;
  #pragma unroll
  for (int i = 0; i < 4; ++i) {
    const int r = by * 32 + ty + i * 8;
    tile[ty + i * 8][tx] = in[(size_t)r * Cn + bx * 32 + tx];
  }
  __syncthreads();
  #pragma unroll
  for (int i = 0; i < 4; ++i) {
    const int cc = bx * 32 + ty + i * 8;
    out[(size_t)cc * R + by * 32 + tx] = f2bf(tile[tx][ty + i * 8]);
  }
}

// ---------------------------------------------------------------- 256x256 GEMM
// C[m][n] = sum_k A[m][k]*BT[n][k].  BM=BN=256, BK=64, 8 waves (2M x 4N),
// 512 threads, 128 KiB LDS (2-slot double buffer).  Per wave: 128x64 output,
// acc[8][4] f32x4.  T1 bijective XCD swizzle; T2 st-style XOR swizzle
// (cb ^= (row&7)<<4) with linear gload_lds dest + pre-swizzled GLOBAL source
// + swizzled ds_read (rule #21); T3-lite: stage tile t+1 before computing
// tile t, single __syncthreads (vmcnt drain + barrier) per K-tile; T5 setprio.
// MODE 0: QKV epilogue (bias + relu/scale -> q [B,H,N,d], kT/vT [B,H,d,N])
// MODE 1: proj epilogue (bias, f32 out [M][768])
template <int MODE>
__global__ __launch_bounds__(512, 2)
void gemm256(const ushort_t* __restrict__ A, const ushort_t* __restrict__ BT,
             const float* __restrict__ bias,
             void* __restrict__ o0, void* __restrict__ o1, void* __restrict__ o2,
             int K, int ntiles) {
  __shared__ __attribute__((aligned(16))) ushort_t As[2][16384];  // [slot][256*64]
  __shared__ __attribute__((aligned(16))) ushort_t Bs[2][16384];

  // T1 bijective XCD-chunk swizzle (m204 form; works for any grid size)
  const int nwg = gridDim.x;
  const int qq = nwg >> 3, rr = nwg & 7;
  const int xcd = blockIdx.x & 7;
  const int idx = blockIdx.x >> 3;
  const int bid = (xcd < rr ? xcd * (qq + 1) : rr * (qq + 1) + (xcd - rr) * qq) + idx;
  const int nt = bid % ntiles, mt = bid / ntiles;

  const int t = threadIdx.x;
  const int w = t >> 6, l = t & 63;
  const int wr = w >> 2, wc = w & 3;          // 2 x 4 wave grid
  const int lr = l & 15, lg = l >> 4;

  const ushort_t* Ap = A + (size_t)mt * 256 * K;
  const ushort_t* Bp = BT + (size_t)nt * 256 * K;

  // staging geometry: thread t covers (row = j*64 + t/8, 16B chunk = t%8)
  const int srow = t >> 3;          // 0..63
  const int scb  = (t & 7) * 16;    // byte offset in 128B row
  // pre-swizzled global source column (involution, bits 4..6 ^= row&7)
  // per j, row = j*64 + srow, row&7 == srow&7 (64 divisible by 8)
  const int gcb = scb ^ ((srow & 7) << 4);

  f32x4 acc[8][4];
  #pragma unroll
  for (int i = 0; i < 8; ++i)
    #pragma unroll
    for (int j = 0; j < 4; ++j) acc[i][j] = (f32x4){0.f, 0.f, 0.f, 0.f};

  const int NT = K >> 6;  // K-tiles of 64

  // ---- prologue: stage tile 0 into slot 0
  #pragma unroll
  for (int j = 0; j < 4; ++j) {
    const int row = j * 64 + srow;
    gload_lds16(Ap + (size_t)row * K + (gcb >> 1), &As[0][row * 64 + (scb >> 1)]);
    gload_lds16(Bp + (size_t)row * K + (gcb >> 1), &Bs[0][row * 64 + (scb >> 1)]);
  }
  __syncthreads();  // drains vmcnt(0) + barrier

  for (int kt = 0; kt < NT; ++kt) {
    const int cur = kt & 1;
    // ---- stage tile kt+1 into the free slot (issued early; lands under MFMA)
    if (kt + 1 < NT) {
      const int k0 = (kt + 1) << 6;
      #pragma unroll
      for (int j = 0; j < 4; ++j) {
        const int row = j * 64 + srow;
        gload_lds16(Ap + (size_t)row * K + k0 + (gcb >> 1),
                    &As[cur ^ 1][row * 64 + (scb >> 1)]);
        gload_lds16(Bp + (size_t)row * K + k0 + (gcb >> 1),
                    &Bs[cur ^ 1][row * 64 + (scb >> 1)]);
      }
    }
    // ---- B fragments for whole K-tile (8 ds_read_b128, swizzled)
    short8 bf[4][2];
    #pragma unroll
    for (int nf = 0; nf < 4; ++nf) {
      const int rb = wc * 64 + nf * 16 + lr;
      const int xr = (rb & 7) << 4;
      #pragma unroll
      for (int ks = 0; ks < 2; ++ks) {
        const int kb = ks * 64 + lg * 16;
        bf[nf][ks] = *(const short8*)&Bs[cur][rb * 64 + ((kb ^ xr) >> 1)];
      }
    }
    // ---- two M-half phases
    #pragma unroll
    for (int qm = 0; qm < 2; ++qm) {
      short8 af[4][2];
      #pragma unroll
      for (int mf = 0; mf < 4; ++mf) {
        const int ra = wr * 128 + qm * 64 + mf * 16 + lr;
        const int xr = (ra & 7) << 4;
        #pragma unroll
        for (int ks = 0; ks < 2; ++ks) {
          const int kb = ks * 64 + lg * 16;
          af[mf][ks] = *(const short8*)&As[cur][ra * 64 + ((kb ^ xr) >> 1)];
        }
      }
      __builtin_amdgcn_s_setprio(1);
      #pragma unroll
      for (int mf = 0; mf < 4; ++mf)
        #pragma unroll
        for (int nf = 0; nf < 4; ++nf)
          #pragma unroll
          for (int ks = 0; ks < 2; ++ks)
            acc[qm * 4 + mf][nf] = __builtin_amdgcn_mfma_f32_16x16x32_bf16(
                af[mf][ks], bf[nf][ks], acc[qm * 4 + mf][nf], 0, 0, 0);
      __builtin_amdgcn_s_setprio(0);
    }
    __syncthreads();  // drain staging loads + retire slot readers
  }

  // ---- epilogue
  if (MODE == 0) {
    ushort_t* q  = (ushort_t*)o0;
    ushort_t* kT = (ushort_t*)o1;
    ushort_t* vT = (ushort_t*)o2;
    #pragma unroll
    for (int nf = 0; nf < 4; ++nf) {
      const int c3 = nt * 256 + wc * 64 + nf * 16 + lr;
      const float bv = bias[c3];
      const int s = (c3 >= 1536) ? 2 : (c3 >= 768 ? 1 : 0);
      const int rem = c3 - s * 768;
      const int h = rem >> 6, dd = rem & 63;
      #pragma unroll
      for (int mi = 0; mi < 8; ++mi) {
        const int mbase = mt * 256 + wr * 128 + mi * 16 + lg * 4;
        #pragma unroll
        for (int r = 0; r < 4; ++r) {
          const int m = mbase + r;
          const int b_ = m / 3136;
          const int n = m - b_ * 3136;
          float v = acc[mi][nf][r] + bv;
          if (s == 0) {
            v = fmaxf(v, 0.f) * 0.125f;
            q[(((size_t)b_ * 12 + h) * 3136 + n) * 64 + dd] = f2bf(v);
          } else if (s == 1) {
            v = fmaxf(v, 0.f);
            kT[(((size_t)b_ * 12 + h) * 64 + dd) * 3136 + n] = f2bf(v);
          } else {
            vT[(((size_t)b_ * 12 + h) * 64 + dd) * 3136 + n] = f2bf(v);
          }
        }
      }
    }
  } else {
    float* O = (float*)o0;
    #pragma unroll
    for (int nf = 0; nf < 4; ++nf) {
      const int c = nt * 256 + wc * 64 + nf * 16 + lr;
      const float bv = bias[c];
      #pragma unroll
      for (int mi = 0; mi < 8; ++mi) {
        const int mbase = mt * 256 + wr * 128 + mi * 16 + lg * 4;
        #pragma unroll
        for (int r = 0; r < 4; ++r)
          O[(size_t)(mbase + r) * 768 + c] = acc[mi][nf][r] + bv;
      }
    }
  }
}

// ---------------------------------------------------------------- context = k^T v
// ctxT[bh][e][d] += sum_n kT[bh][d][n] * vT[bh][e][n]; 7 N-splits of 448, atomics.
__global__ __launch_bounds__(64)
void ctx_k(const ushort_t* __restrict__ kT, const ushort_t* __restrict__ vT,
           float* __restrict__ ctxT) {
  __shared__ __attribute__((aligned(16))) ushort_t Ks[64 * 64];
  __shared__ __attribute__((aligned(16))) ushort_t Vs[64 * 64];
  const int bid = blockIdx.x;
  const int s = bid % 7, bh = bid / 7;
  const int n0 = s * 448;
  const int t = threadIdx.x;
  const int lr = t & 15, lg = t >> 4;
  const ushort_t* kp = kT + (size_t)bh * 64 * 3136;
  const ushort_t* vp = vT + (size_t)bh * 64 * 3136;
  const int srow = t >> 3, scol = (t & 7) * 8;

  f32x4 acc[4][4];
  #pragma unroll
  for (int i = 0; i < 4; ++i)
    #pragma unroll
    for (int j = 0; j < 4; ++j) acc[i][j] = (f32x4){0.f, 0.f, 0.f, 0.f};

  for (int c = 0; c < 7; ++c) {
    const int nb = n0 + c * 64;
    #pragma unroll
    for (int i = 0; i < 8; ++i) {
      gload_lds16(kp + (size_t)(i * 8 + srow) * 3136 + nb + scol, &Ks[(i * 8 + srow) * 64 + scol]);
      gload_lds16(vp + (size_t)(i * 8 + srow) * 3136 + nb + scol, &Vs[(i * 8 + srow) * 64 + scol]);
    }
    __syncthreads();
    #pragma unroll
    for (int kk = 0; kk < 2; ++kk) {
      short8 a[4], bfr[4];
      #pragma unroll
      for (int mf = 0; mf < 4; ++mf)
        a[mf] = *(const short8*)&Ks[(mf * 16 + lr) * 64 + kk * 32 + lg * 8];
      #pragma unroll
      for (int nf = 0; nf < 4; ++nf)
        bfr[nf] = *(const short8*)&Vs[(nf * 16 + lr) * 64 + kk * 32 + lg * 8];
      #pragma unroll
      for (int mf = 0; mf < 4; ++mf)
        #pragma unroll
        for (int nf = 0; nf < 4; ++nf)
          acc[mf][nf] = __builtin_amdgcn_mfma_f32_16x16x32_bf16(a[mf], bfr[nf], acc[mf][nf], 0, 0, 0);
    }
    __syncthreads();
  }
  float* cp = ctxT + (size_t)bh * 4096;
  #pragma unroll
  for (int mf = 0; mf < 4; ++mf)
    #pragma unroll
    for (int nf = 0; nf < 4; ++nf)
      #pragma unroll
      for (int r = 0; r < 4; ++r)
        atomicAdd(&cp[(nf * 16 + lr) * 64 + mf * 16 + lg * 4 + r], acc[mf][nf][r]);
}

// ---------------------------------------------------------------- out = q @ ctx
// out[b][n][h*64+e] = sum_d q[bh][n][d] * ctx[d][e]   (ctxT stored [bh][e][d])
__global__ __launch_bounds__(256)
void attnout_k(const ushort_t* __restrict__ q, const float* __restrict__ ctxT,
               ushort_t* __restrict__ out) {
  __shared__ __attribute__((aligned(16))) ushort_t Qs[256 * 64];
  __shared__ __attribute__((aligned(16))) ushort_t Cs[64 * 64];
  const int bid = blockIdx.x;
  const int tile = bid % 13, bh = bid / 13;
  const int b_ = bh / 12, h = bh - b_ * 12;
  const int n0 = tile * 256;
  const int t = threadIdx.x;
  const int w = t >> 6, l = t & 63;
  const int lr = l & 15, lg = l >> 4;
  const ushort_t* qp = q + (size_t)bh * 3136 * 64;

  {  // stage ctx^T -> Cs (f32 -> bf16), linear
    const float4* cp = (const float4*)(ctxT + (size_t)bh * 4096);
    #pragma unroll
    for (int i = 0; i < 4; ++i) {
      const int j = i * 256 + t;
      float4 f = cp[j];
      ((ushort4*)Cs)[j] = make_ushort4(f2bf(f.x), f2bf(f.y), f2bf(f.z), f2bf(f.w));
    }
  }
  const int srow = t >> 3, scol = (t & 7) * 8;
  #pragma unroll
  for (int i = 0; i < 8; ++i)
    gload_lds16(qp + (size_t)(n0 + i * 32 + srow) * 64 + scol, &Qs[(i * 32 + srow) * 64 + scol]);
  __syncthreads();

  f32x4 acc[4][4];
  #pragma unroll
  for (int i = 0; i < 4; ++i)
    #pragma unroll
    for (int j = 0; j < 4; ++j) acc[i][j] = (f32x4){0.f, 0.f, 0.f, 0.f};

  #pragma unroll
  for (int kk = 0; kk < 2; ++kk) {
    short8 a[4], bfr[4];
    #pragma unroll
    for (int mf = 0; mf < 4; ++mf)
      a[mf] = *(const short8*)&Qs[(w * 64 + mf * 16 + lr) * 64 + kk * 32 + lg * 8];
    #pragma unroll
    for (int nf = 0; nf < 4; ++nf)
      bfr[nf] = *(const short8*)&Cs[(nf * 16 + lr) * 64 + kk * 32 + lg * 8];
    #pragma unroll
    for (int mf = 0; mf < 4; ++mf)
      #pragma unroll
      for (int nf = 0; nf < 4; ++nf)
        acc[mf][nf] = __builtin_amdgcn_mfma_f32_16x16x32_bf16(a[mf], bfr[nf], acc[mf][nf], 0, 0, 0);
  }

  ushort_t* op = out + (size_t)b_ * 3136 * 768 + h * 64;
  #pragma unroll
  for (int mf = 0; mf < 4; ++mf) {
    const int nb = n0 + w * 64 + mf * 16 + lg * 4;
    #pragma unroll
    for (int r = 0; r < 4; ++r) {
      const int n = nb + r;
      if (n < 3136) {
        #pragma unroll
        for (int nf = 0; nf < 4; ++nf)
          op[(size_t)n * 768 + nf * 16 + lr] = f2bf(acc[mf][nf][r]);
      }
    }
  }
}

// ---------------------------------------------------------------- depthwise 3x3
__global__ __launch_bounds__(768)
void dwconv_k(const ushort_t* __restrict__ in, const float* __restrict__ w9,
              const float* __restrict__ wb, ushort_t* __restrict__ out) {
  const int bn = blockIdx.x;
  const int b_ = bn / 3136, n = bn - b_ * 3136;
  const int y = n / 56, x = n - y * 56;
  const int c = threadIdx.x;
  const ushort_t* ip = in + (size_t)b_ * 3136 * 768 + c;
  float wv[9];
  #pragma unroll
  for (int i = 0; i < 9; ++i) wv[i] = w9[c * 9 + i];
  float acc = wb[c];
  #pragma unroll
  for (int dy = 0; dy < 3; ++dy) {
    const int yy = y + dy - 1;
    if ((unsigned)yy < 56u) {
      #pragma unroll
      for (int dx = 0; dx < 3; ++dx) {
        const int xx = x + dx - 1;
        if ((unsigned)xx < 56u)
          acc += bf2f(ip[(size_t)(yy * 56 + xx) * 768]) * wv[dy * 3 + dx];
      }
    }
  }
  out[(size_t)bn * 768 + c] = f2bf(acc);
}

// ---------------------------------------------------------------- launch
extern "C" void kernel_launch(void* const* d_in, const int* in_sizes, int n_in,
                              void* d_out, int out_size, void* d_ws, size_t ws_size,
                              hipStream_t stream) {
  (void)in_sizes; (void)n_in; (void)out_size; (void)ws_size;
  const float* x      = (const float*)d_in[0];
  const float* qkv_w  = (const float*)d_in[1];
  const float* qkv_b  = (const float*)d_in[2];
  const float* dw_w   = (const float*)d_in[3];
  const float* dw_b   = (const float*)d_in[4];
  const float* proj_w = (const float*)d_in[5];
  const float* proj_b = (const float*)d_in[6];
  float* out = (float*)d_out;

  char* ws = (char*)d_ws;
  const size_t SZ = (size_t)50176 * 768 * 2;  // 77,070,336 B per activation tensor
  ushort_t* xbf  = (ushort_t*)(ws);           // x bf16; later reused as attn-out
  ushort_t* attn = xbf;
  ushort_t* q    = (ushort_t*)(ws + SZ);      // q [B,H,N,d]; later reused as conv-out
  ushort_t* cvo  = q;
  ushort_t* kT   = (ushort_t*)(ws + 2 * SZ);  // [B,H,d,N]
  ushort_t* vT   = (ushort_t*)(ws + 3 * SZ);  // [B,H,d,N]
  ushort_t* wt1  = (ushort_t*)(ws + 4 * SZ);                        // qkv_w^T bf16 [2304][768]
  ushort_t* wt2  = (ushort_t*)(ws + 4 * SZ + 3538944);              // proj_w^T bf16 [768][768]
  float*    ctx  = (float*)(ws + 4 * SZ + 3538944 + 1179648);       // [192][64][64] f32

  hipMemsetAsync(ctx, 0, (size_t)192 * 4096 * 4, stream);
  cvt_x_k<<<37632, 256, 0, stream>>>((const float4*)x, (ushort4*)xbf);
  transp_k<<<1728, 256, 0, stream>>>(qkv_w, wt1, 768, 2304);
  transp_k<<<576, 256, 0, stream>>>(proj_w, wt2, 768, 768);
  gemm256<0><<<196 * 9, 512, 0, stream>>>(xbf, wt1, qkv_b, q, kT, vT, 768, 9);
  ctx_k<<<192 * 7, 64, 0, stream>>>(kT, vT, ctx);
  attnout_k<<<192 * 13, 256, 0, stream>>>(q, ctx, attn);
  dwconv_k<<<50176, 768, 0, stream>>>(attn, dw_w, dw_b, cvo);
  gemm256<1><<<196 * 3, 512, 0, stream>>>(cvo, wt2, proj_b, out, nullptr, nullptr, 768, 3);
}

// Round 6
// 1031.102 us; speedup vs baseline: 1.0985x; 1.0985x over previous
//
#include <hip/hip_runtime.h>

typedef unsigned short ushort_t;
typedef __attribute__((ext_vector_type(8))) short short8;
typedef __attribute__((ext_vector_type(4))) float f32x4;

#define DEV __device__ __forceinline__

DEV unsigned short f2bf(float f) {
  unsigned int u = __float_as_uint(f);
  u += 0x7FFFu + ((u >> 16) & 1u);           // round-to-nearest-even
  return (unsigned short)(u >> 16);
}
DEV float bf2f(unsigned short h) { return __uint_as_float(((unsigned int)h) << 16); }

DEV void gload_lds16(const void* g, void* l) {
  __builtin_amdgcn_global_load_lds((const __attribute__((address_space(1))) void*)g,
                                   (__attribute__((address_space(3))) void*)l, 16, 0, 0);
}

// ---------------------------------------------------------------- converts
__global__ void cvt_x_k(const float4* __restrict__ in, ushort4* __restrict__ out) {
  const int i = blockIdx.x * 256 + threadIdx.x;
  float4 f = in[i];
  out[i] = make_ushort4(f2bf(f.x), f2bf(f.y), f2bf(f.z), f2bf(f.w));
}

// in [R][Cn] f32 -> out [Cn][R] bf16   (tiled transpose)
__global__ __launch_bounds__(256)
void transp_k(const float* __restrict__ in, ushort_t* __restrict__ out, int R, int Cn) {
  __shared__ float tile[32][33];
  const int ctiles = Cn >> 5;
  const int bx = blockIdx.x % ctiles;
  const int by = blockIdx.x / ctiles;
  const int tx = threadIdx.x & 31, ty = threadIdx.x >> 5;
  #pragma unroll
  for (int i = 0; i < 4; ++i) {
    const int r = by * 32 + ty + i * 8;
    tile[ty + i * 8][tx] = in[(size_t)r * Cn + bx * 32 + tx];
  }
  __syncthreads();
  #pragma unroll
  for (int i = 0; i < 4; ++i) {
    const int cc = bx * 32 + ty + i * 8;
    out[(size_t)cc * R + by * 32 + tx] = f2bf(tile[tx][ty + i * 8]);
  }
}

// ---------------------------------------------------------------- 256x256 GEMM, T4 pipeline
// C[m][n] = sum_k A[m][k]*BT[n][k].  BM=BN=256, BK=32, 8 waves (2M x 4N),
// 512 threads, 3-slot LDS ring (96 KiB).  T4 counted vmcnt: stage tile kt+2
// while computing kt; per-iter wait is vmcnt(4) (tile kt's 4 loads of the 8
// outstanding) -- loads stay in flight ACROSS the barrier; vmcnt(0) only on
// the final tile.  One raw s_barrier per tile (write-after-read safe: slot
// kt+2 == slot kt-1 mod 3, whose readers latched their data before crossing
// barrier(kt)).  sched_barrier(0) fences around the body (rule #18).
// T2 XOR swizzle for 64B rows: byte ^= (row&3)<<4, applied on BOTH the
// pre-swizzled global source and the ds_read address (linear LDS dest).
// T1 bijective XCD chunking.  T5 setprio around the MFMA cluster.
// MODE 0: QKV epilogue (bias + relu/scale -> q [B,H,N,d], kT/vT [B,H,d,N])
// MODE 1: proj epilogue (bias, f32 out [M][768])
template <int MODE>
__global__ __launch_bounds__(512, 2)
void gemm256p(const ushort_t* __restrict__ A, const ushort_t* __restrict__ BT,
              const float* __restrict__ bias,
              void* __restrict__ o0, void* __restrict__ o1, void* __restrict__ o2,
              int K, int ntiles) {
  __shared__ __attribute__((aligned(16))) ushort_t As[3][256 * 32];
  __shared__ __attribute__((aligned(16))) ushort_t Bs[3][256 * 32];

  // T1 bijective XCD-chunk swizzle (m204 form)
  const int nwg = gridDim.x;
  const int qq = nwg >> 3, rr = nwg & 7;
  const int xcd = blockIdx.x & 7;
  const int idx = blockIdx.x >> 3;
  const int bid = (xcd < rr ? xcd * (qq + 1) : rr * (qq + 1) + (xcd - rr) * qq) + idx;
  const int nt = bid % ntiles, mt = bid / ntiles;

  const int t = threadIdx.x;
  const int w = t >> 6, l = t & 63;
  const int wr = w >> 2, wc = w & 3;          // 2 x 4 wave grid
  const int lr = l & 15, lg = l >> 4;

  const ushort_t* Ap = A + (size_t)mt * 256 * K;
  const ushort_t* Bp = BT + (size_t)nt * 256 * K;

  // staging: thread t covers rows {t>>2, t>>2 + 128}, 16B chunk (t&3) of 64B row
  const int srow = t >> 2;               // 0..127
  const int scb  = (t & 3) * 16;         // byte offset in 64B row
  const int gcb  = scb ^ ((srow & 3) << 4);  // pre-swizzled global source byte
  // (row+128)&3 == row&3, so one gcb serves both j rows

  f32x4 acc[8][4];
  #pragma unroll
  for (int i = 0; i < 8; ++i)
    #pragma unroll
    for (int j = 0; j < 4; ++j) acc[i][j] = (f32x4){0.f, 0.f, 0.f, 0.f};

  const int NT = K >> 5;  // K-tiles of 32

#define STAGE_TILE(SLOT, KT)                                                     \
  {                                                                              \
    const int k0_ = (KT) << 5;                                                   \
    _Pragma("unroll")                                                            \
    for (int j = 0; j < 2; ++j) {                                                \
      const int row_ = j * 128 + srow;                                           \
      gload_lds16(Ap + (size_t)row_ * K + k0_ + (gcb >> 1),                      \
                  &As[SLOT][row_ * 32 + (scb >> 1)]);                            \
      gload_lds16(Bp + (size_t)row_ * K + k0_ + (gcb >> 1),                      \
                  &Bs[SLOT][row_ * 32 + (scb >> 1)]);                            \
    }                                                                            \
  }

  // prologue: stage tiles 0,1 -> 8 loads in flight per wave
  STAGE_TILE(0, 0);
  STAGE_TILE(1, 1);

  for (int kt = 0; kt < NT; ++kt) {
    if (kt < NT - 1) {
      asm volatile("s_waitcnt vmcnt(4)" ::: "memory");   // tile kt landed; kt+1 in flight
    } else {
      asm volatile("s_waitcnt vmcnt(0)" ::: "memory");   // last tile: drain
    }
    __builtin_amdgcn_s_barrier();
    __builtin_amdgcn_sched_barrier(0);

    const int sl = kt % 3;
    if (kt + 2 < NT) {
      const int s2 = (kt + 2) % 3;
      STAGE_TILE(s2, kt + 2);
    }

    // B fragments (4 x ds_read_b128, swizzled)
    short8 bfr[4];
    #pragma unroll
    for (int nf = 0; nf < 4; ++nf) {
      const int rb = wc * 64 + nf * 16 + lr;
      bfr[nf] = *(const short8*)&Bs[sl][rb * 32 + (((lg * 16) ^ ((rb & 3) << 4)) >> 1)];
    }
    // A fragments (8 x ds_read_b128, swizzled)
    short8 af[8];
    #pragma unroll
    for (int mi = 0; mi < 8; ++mi) {
      const int ra = wr * 128 + mi * 16 + lr;
      af[mi] = *(const short8*)&As[sl][ra * 32 + (((lg * 16) ^ ((ra & 3) << 4)) >> 1)];
    }

    __builtin_amdgcn_s_setprio(1);
    #pragma unroll
    for (int mi = 0; mi < 8; ++mi)
      #pragma unroll
      for (int nf = 0; nf < 4; ++nf)
        acc[mi][nf] = __builtin_amdgcn_mfma_f32_16x16x32_bf16(af[mi], bfr[nf],
                                                              acc[mi][nf], 0, 0, 0);
    __builtin_amdgcn_s_setprio(0);
    __builtin_amdgcn_sched_barrier(0);
  }
#undef STAGE_TILE

  // ---- epilogue
  if (MODE == 0) {
    ushort_t* q  = (ushort_t*)o0;
    ushort_t* kT = (ushort_t*)o1;
    ushort_t* vT = (ushort_t*)o2;
    #pragma unroll
    for (int nf = 0; nf < 4; ++nf) {
      const int c3 = nt * 256 + wc * 64 + nf * 16 + lr;
      const float bv = bias[c3];
      const int s = (c3 >= 1536) ? 2 : (c3 >= 768 ? 1 : 0);
      const int rem = c3 - s * 768;
      const int h = rem >> 6, dd = rem & 63;
      #pragma unroll
      for (int mi = 0; mi < 8; ++mi) {
        const int mbase = mt * 256 + wr * 128 + mi * 16 + lg * 4;
        #pragma unroll
        for (int r = 0; r < 4; ++r) {
          const int m = mbase + r;
          const int b_ = m / 3136;
          const int n = m - b_ * 3136;
          float v = acc[mi][nf][r] + bv;
          if (s == 0) {
            v = fmaxf(v, 0.f) * 0.125f;
            q[(((size_t)b_ * 12 + h) * 3136 + n) * 64 + dd] = f2bf(v);
          } else if (s == 1) {
            v = fmaxf(v, 0.f);
            kT[(((size_t)b_ * 12 + h) * 64 + dd) * 3136 + n] = f2bf(v);
          } else {
            vT[(((size_t)b_ * 12 + h) * 64 + dd) * 3136 + n] = f2bf(v);
          }
        }
      }
    }
  } else {
    float* O = (float*)o0;
    #pragma unroll
    for (int nf = 0; nf < 4; ++nf) {
      const int c = nt * 256 + wc * 64 + nf * 16 + lr;
      const float bv = bias[c];
      #pragma unroll
      for (int mi = 0; mi < 8; ++mi) {
        const int mbase = mt * 256 + wr * 128 + mi * 16 + lg * 4;
        #pragma unroll
        for (int r = 0; r < 4; ++r)
          O[(size_t)(mbase + r) * 768 + c] = acc[mi][nf][r] + bv;
      }
    }
  }
}

// ---------------------------------------------------------------- context = k^T v
// ctxT[bh][e][d] += sum_n kT[bh][d][n] * vT[bh][e][n]; 7 N-splits of 448, atomics.
__global__ __launch_bounds__(64)
void ctx_k(const ushort_t* __restrict__ kT, const ushort_t* __restrict__ vT,
           float* __restrict__ ctxT) {
  __shared__ __attribute__((aligned(16))) ushort_t Ks[64 * 64];
  __shared__ __attribute__((aligned(16))) ushort_t Vs[64 * 64];
  const int bid = blockIdx.x;
  const int s = bid % 7, bh = bid / 7;
  const int n0 = s * 448;
  const int t = threadIdx.x;
  const int lr = t & 15, lg = t >> 4;
  const ushort_t* kp = kT + (size_t)bh * 64 * 3136;
  const ushort_t* vp = vT + (size_t)bh * 64 * 3136;
  const int srow = t >> 3, scol = (t & 7) * 8;

  f32x4 acc[4][4];
  #pragma unroll
  for (int i = 0; i < 4; ++i)
    #pragma unroll
    for (int j = 0; j < 4; ++j) acc[i][j] = (f32x4){0.f, 0.f, 0.f, 0.f};

  for (int c = 0; c < 7; ++c) {
    const int nb = n0 + c * 64;
    #pragma unroll
    for (int i = 0; i < 8; ++i) {
      gload_lds16(kp + (size_t)(i * 8 + srow) * 3136 + nb + scol, &Ks[(i * 8 + srow) * 64 + scol]);
      gload_lds16(vp + (size_t)(i * 8 + srow) * 3136 + nb + scol, &Vs[(i * 8 + srow) * 64 + scol]);
    }
    __syncthreads();
    #pragma unroll
    for (int kk = 0; kk < 2; ++kk) {
      short8 a[4], bfr[4];
      #pragma unroll
      for (int mf = 0; mf < 4; ++mf)
        a[mf] = *(const short8*)&Ks[(mf * 16 + lr) * 64 + kk * 32 + lg * 8];
      #pragma unroll
      for (int nf = 0; nf < 4; ++nf)
        bfr[nf] = *(const short8*)&Vs[(nf * 16 + lr) * 64 + kk * 32 + lg * 8];
      #pragma unroll
      for (int mf = 0; mf < 4; ++mf)
        #pragma unroll
        for (int nf = 0; nf < 4; ++nf)
          acc[mf][nf] = __builtin_amdgcn_mfma_f32_16x16x32_bf16(a[mf], bfr[nf], acc[mf][nf], 0, 0, 0);
    }
    __syncthreads();
  }
  float* cp = ctxT + (size_t)bh * 4096;
  #pragma unroll
  for (int mf = 0; mf < 4; ++mf)
    #pragma unroll
    for (int nf = 0; nf < 4; ++nf)
      #pragma unroll
      for (int r = 0; r < 4; ++r)
        atomicAdd(&cp[(nf * 16 + lr) * 64 + mf * 16 + lg * 4 + r], acc[mf][nf][r]);
}

// ---------------------------------------------------------------- out = q @ ctx
// out[b][n][h*64+e] = sum_d q[bh][n][d] * ctx[d][e]   (ctxT stored [bh][e][d])
__global__ __launch_bounds__(256)
void attnout_k(const ushort_t* __restrict__ q, const float* __restrict__ ctxT,
               ushort_t* __restrict__ out) {
  __shared__ __attribute__((aligned(16))) ushort_t Qs[256 * 64];
  __shared__ __attribute__((aligned(16))) ushort_t Cs[64 * 64];
  const int bid = blockIdx.x;
  const int tile = bid % 13, bh = bid / 13;
  const int b_ = bh / 12, h = bh - b_ * 12;
  const int n0 = tile * 256;
  const int t = threadIdx.x;
  const int w = t >> 6, l = t & 63;
  const int lr = l & 15, lg = l >> 4;
  const ushort_t* qp = q + (size_t)bh * 3136 * 64;

  {  // stage ctx^T -> Cs (f32 -> bf16), linear
    const float4* cp = (const float4*)(ctxT + (size_t)bh * 4096);
    #pragma unroll
    for (int i = 0; i < 4; ++i) {
      const int j = i * 256 + t;
      float4 f = cp[j];
      ((ushort4*)Cs)[j] = make_ushort4(f2bf(f.x), f2bf(f.y), f2bf(f.z), f2bf(f.w));
    }
  }
  const int srow = t >> 3, scol = (t & 7) * 8;
  #pragma unroll
  for (int i = 0; i < 8; ++i)
    gload_lds16(qp + (size_t)(n0 + i * 32 + srow) * 64 + scol, &Qs[(i * 32 + srow) * 64 + scol]);
  __syncthreads();

  f32x4 acc[4][4];
  #pragma unroll
  for (int i = 0; i < 4; ++i)
    #pragma unroll
    for (int j = 0; j < 4; ++j) acc[i][j] = (f32x4){0.f, 0.f, 0.f, 0.f};

  #pragma unroll
  for (int kk = 0; kk < 2; ++kk) {
    short8 a[4], bfr[4];
    #pragma unroll
    for (int mf = 0; mf < 4; ++mf)
      a[mf] = *(const short8*)&Qs[(w * 64 + mf * 16 + lr) * 64 + kk * 32 + lg * 8];
    #pragma unroll
    for (int nf = 0; nf < 4; ++nf)
      bfr[nf] = *(const short8*)&Cs[(nf * 16 + lr) * 64 + kk * 32 + lg * 8];
    #pragma unroll
    for (int mf = 0; mf < 4; ++mf)
      #pragma unroll
      for (int nf = 0; nf < 4; ++nf)
        acc[mf][nf] = __builtin_amdgcn_mfma_f32_16x16x32_bf16(a[mf], bfr[nf], acc[mf][nf], 0, 0, 0);
  }

  ushort_t* op = out + (size_t)b_ * 3136 * 768 + h * 64;
  #pragma unroll
  for (int mf = 0; mf < 4; ++mf) {
    const int nb = n0 + w * 64 + mf * 16 + lg * 4;
    #pragma unroll
    for (int r = 0; r < 4; ++r) {
      const int n = nb + r;
      if (n < 3136) {
        #pragma unroll
        for (int nf = 0; nf < 4; ++nf)
          op[(size_t)n * 768 + nf * 16 + lr] = f2bf(acc[mf][nf][r]);
      }
    }
  }
}

// ---------------------------------------------------------------- depthwise 3x3
// One block per (b, y) row: 384 threads, 2 channels/thread (ushort2 loads, G13),
// sliding 3-column window in named registers (rule #20): 3 loads per output.
__global__ __launch_bounds__(384)
void dwconv_k(const ushort_t* __restrict__ in, const float* __restrict__ w9,
              const float* __restrict__ wb, ushort_t* __restrict__ out) {
  const int by = blockIdx.x;               // b*56 + y
  const int b_ = by / 56, y = by - b_ * 56;
  const int c0 = threadIdx.x * 2;
  const ushort_t* ip = in + (size_t)b_ * 3136 * 768;
  ushort_t* op = out + ((size_t)b_ * 3136 + (size_t)y * 56) * 768 + c0;

  float w0[9], w1[9];
  #pragma unroll
  for (int i = 0; i < 9; ++i) { w0[i] = w9[c0 * 9 + i]; w1[i] = w9[c0 * 9 + 9 + i]; }
  const float bb0 = wb[c0], bb1 = wb[c0 + 1];

  const int ym = y - 1, yp = y + 1;
  const bool ymok = (ym >= 0), ypok = (yp < 56);
  const size_t r0 = ymok ? ((size_t)(ym * 56) * 768 + c0) : 0;
  const size_t r1 = (size_t)(y * 56) * 768 + c0;
  const size_t r2 = ypok ? ((size_t)(yp * 56) * 768 + c0) : 0;

  auto ld = [&](size_t rbase, bool ok, int xx) -> float2 {
    if (!ok || xx >= 56) return make_float2(0.f, 0.f);
    const unsigned int u = *(const unsigned int*)(ip + rbase + (size_t)xx * 768);
    return make_float2(bf2f((ushort_t)(u & 0xffffu)), bf2f((ushort_t)(u >> 16)));
  };

  // window columns {x-1, x, x+1}; named registers (a=top row, b=mid, c=bot)
  float2 a0 = make_float2(0.f, 0.f), a1 = ld(r0, ymok, 0), a2 = ld(r0, ymok, 1);
  float2 b0 = make_float2(0.f, 0.f), b1 = ld(r1, true, 0), b2 = ld(r1, true, 1);
  float2 c0v = make_float2(0.f, 0.f), c1 = ld(r2, ypok, 0), c2 = ld(r2, ypok, 1);

  for (int x = 0; x < 56; ++x) {
    float s0 = bb0 + a0.x * w0[0] + a1.x * w0[1] + a2.x * w0[2]
                   + b0.x * w0[3] + b1.x * w0[4] + b2.x * w0[5]
                   + c0v.x * w0[6] + c1.x * w0[7] + c2.x * w0[8];
    float s1 = bb1 + a0.y * w1[0] + a1.y * w1[1] + a2.y * w1[2]
                   + b0.y * w1[3] + b1.y * w1[4] + b2.y * w1[5]
                   + c0v.y * w1[6] + c1.y * w1[7] + c2.y * w1[8];
    *(unsigned int*)(op + (size_t)x * 768) =
        ((unsigned int)f2bf(s1) << 16) | (unsigned int)f2bf(s0);
    // slide window
    a0 = a1; a1 = a2; a2 = ld(r0, ymok, x + 2);
    b0 = b1; b1 = b2; b2 = ld(r1, true, x + 2);
    c0v = c1; c1 = c2; c2 = ld(r2, ypok, x + 2);
  }
}

// ---------------------------------------------------------------- launch
extern "C" void kernel_launch(void* const* d_in, const int* in_sizes, int n_in,
                              void* d_out, int out_size, void* d_ws, size_t ws_size,
                              hipStream_t stream) {
  (void)in_sizes; (void)n_in; (void)out_size; (void)ws_size;
  const float* x      = (const float*)d_in[0];
  const float* qkv_w  = (const float*)d_in[1];
  const float* qkv_b  = (const float*)d_in[2];
  const float* dw_w   = (const float*)d_in[3];
  const float* dw_b   = (const float*)d_in[4];
  const float* proj_w = (const float*)d_in[5];
  const float* proj_b = (const float*)d_in[6];
  float* out = (float*)d_out;

  char* ws = (char*)d_ws;
  const size_t SZ = (size_t)50176 * 768 * 2;  // 77,070,336 B per activation tensor
  ushort_t* xbf  = (ushort_t*)(ws);           // x bf16; later reused as attn-out
  ushort_t* attn = xbf;
  ushort_t* q    = (ushort_t*)(ws + SZ);      // q [B,H,N,d]; later reused as conv-out
  ushort_t* cvo  = q;
  ushort_t* kT   = (ushort_t*)(ws + 2 * SZ);  // [B,H,d,N]
  ushort_t* vT   = (ushort_t*)(ws + 3 * SZ);  // [B,H,d,N]
  ushort_t* wt1  = (ushort_t*)(ws + 4 * SZ);                        // qkv_w^T bf16 [2304][768]
  ushort_t* wt2  = (ushort_t*)(ws + 4 * SZ + 3538944);              // proj_w^T bf16 [768][768]
  float*    ctx  = (float*)(ws + 4 * SZ + 3538944 + 1179648);       // [192][64][64] f32

  hipMemsetAsync(ctx, 0, (size_t)192 * 4096 * 4, stream);
  cvt_x_k<<<37632, 256, 0, stream>>>((const float4*)x, (ushort4*)xbf);
  transp_k<<<1728, 256, 0, stream>>>(qkv_w, wt1, 768, 2304);
  transp_k<<<576, 256, 0, stream>>>(proj_w, wt2, 768, 768);
  gemm256p<0><<<196 * 9, 512, 0, stream>>>(xbf, wt1, qkv_b, q, kT, vT, 768, 9);
  ctx_k<<<192 * 7, 64, 0, stream>>>(kT, vT, ctx);
  attnout_k<<<192 * 13, 256, 0, stream>>>(q, ctx, attn);
  dwconv_k<<<896, 384, 0, stream>>>(attn, dw_w, dw_b, cvo);
  gemm256p<1><<<196 * 3, 512, 0, stream>>>(cvo, wt2, proj_b, out, nullptr, nullptr, 768, 3);
}